// Round 10
// baseline (59.550 us; speedup 1.0000x reference)
//
#include <hip/hip_runtime.h>
#include <math.h>

#define NROWS 1546
#define INDIM 1546
#define ODIM  64
#define NDRUG 1373
#define MINN  1e-15f
#define MAXNRM 0.996f   // (1 - 4e-3)/sqrt(c), c=1

#define KS1  16         // K-splits for liner GEMM
#define CH1  100        // K-chunk (last = 1546-15*100 = 46)
#define KS2  8          // K-splits for agg GEMM
#define CH2  200        // K-chunk (last = 146)
#define RSTR 200        // LDS row stride for agg staging
#define NRG  194        // row-groups of 8
#define QSTR 256        // packed quad stride: idx = (k>>2)*QSTR + col*4 + (k&3)
#define NQ   387        // ceil(1546/4)

__device__ __forceinline__ float artanh_(float x) {
    x = fminf(fmaxf(x, -1.0f + 1e-7f), 1.0f - 1e-7f);
    return 0.5f * (log1pf(x) - log1pf(-x));
}

__device__ __forceinline__ float wsum(float v) {
#pragma unroll
    for (int off = 32; off > 0; off >>= 1) v += __shfl_xor(v, off, 64);
    return v;
}

// ---- kernel 1: split-K x@W^T; W staged per-block from NATIVE layout (no prep) ----
__global__ __launch_bounds__(256) void gemm_liner(
    const float* __restrict__ X, const float* __restrict__ Wd, const float* __restrict__ Wm,
    float* __restrict__ part, float* __restrict__ pnorm) {
    __shared__ __align__(16) float xs[8 * CH1];
    __shared__ __align__(16) float wsl[64 * CH1];   // [out][k], stride 100 dwords
    int tid = threadIdx.x, wave = tid >> 6, lane = tid & 63;
    int row0 = blockIdx.x * 8;
    int kc = blockIdx.y;
    int k0 = kc * CH1;                 // multiple of 4
    int len = min(INDIM - k0, CH1);    // 100 or 46

    {   // stage 8 x-rows (32 threads/row, float2) + fused partial norms
        int r = tid >> 5, c0 = tid & 31;
        int gr = min(row0 + r, NROWS - 1);
        const float2* src = (const float2*)(X + (size_t)gr * INDIM + k0);
        float2* dst = (float2*)&xs[r * CH1];
        int len2 = len >> 1;
        float ss = 0.f;
        for (int c = c0; c < len2; c += 32) {
            float2 v = src[c];
            dst[c] = v;
            ss = fmaf(v.x, v.x, fmaf(v.y, v.y, ss));
        }
#pragma unroll
        for (int off = 16; off > 0; off >>= 1) ss += __shfl_xor(ss, off, 64);
        if (c0 == 0 && row0 + r < NROWS) pnorm[(row0 + r) * KS1 + kc] = ss;
    }
    {   // stage W chunk 64 x len from native [64][1546] (row-major, float2)
        const float* Wsrc = (row0 < NDRUG) ? Wd : Wm;
        if (len == CH1) {
            for (int idx = tid; idx < 64 * 50; idx += 256) {
                int r = idx / 50, c = idx - r * 50;
                *(float2*)&wsl[r * CH1 + 2 * c] =
                    *(const float2*)(Wsrc + (size_t)r * INDIM + k0 + 2 * c);
            }
        } else {   // len == 46
            for (int idx = tid; idx < 64 * 23; idx += 256) {
                int r = idx / 23, c = idx - r * 23;
                *(float2*)&wsl[r * CH1 + 2 * c] =
                    *(const float2*)(Wsrc + (size_t)r * INDIM + k0 + 2 * c);
            }
        }
    }
    __syncthreads();

    const float* wl = wsl + lane * CH1;   // stride 100 dwords: 8 dwords/bank structural min
    bool uni = (row0 + 7 < NDRUG) || (row0 >= NDRUG);
    if (uni) {
        const float* xa = xs + (2 * wave) * CH1;
        const float* xb = xs + (2 * wave + 1) * CH1;
        float acc0 = 0.f, acc1 = 0.f;
        int kk = 0;
#pragma unroll 2
        for (; kk + 4 <= len; kk += 4) {
            float4 w = *(const float4*)(wl + kk);
            float4 a = *(const float4*)(xa + kk);
            float4 b = *(const float4*)(xb + kk);
            acc0 = fmaf(a.x, w.x, acc0); acc0 = fmaf(a.y, w.y, acc0);
            acc0 = fmaf(a.z, w.z, acc0); acc0 = fmaf(a.w, w.w, acc0);
            acc1 = fmaf(b.x, w.x, acc1); acc1 = fmaf(b.y, w.y, acc1);
            acc1 = fmaf(b.z, w.z, acc1); acc1 = fmaf(b.w, w.w, acc1);
        }
        for (; kk < len; ++kk) {       // len=46: 2 scalar iters
            float w = wl[kk];
            acc0 = fmaf(xa[kk], w, acc0);
            acc1 = fmaf(xb[kk], w, acc1);
        }
        int g0 = row0 + 2 * wave, g1 = g0 + 1;
        if (g0 < NROWS) part[(size_t)g0 * (KS1 * 64) + kc * 64 + lane] = acc0;
        if (g1 < NROWS) part[(size_t)g1 * (KS1 * 64) + kc * 64 + lane] = acc1;
    } else {
        // boundary row-group (rows straddle 1373): LDS holds Wd; micr rows read Wm global
#pragma unroll
        for (int j = 0; j < 2; ++j) {
            int r = 2 * wave + j, g = row0 + r;
            const float* xr = xs + r * CH1;
            float acc = 0.f;
            if (g < NDRUG) {
                int kk = 0;
                for (; kk + 4 <= len; kk += 4) {
                    float4 w = *(const float4*)(wl + kk);
                    float4 a = *(const float4*)(xr + kk);
                    acc = fmaf(a.x, w.x, acc); acc = fmaf(a.y, w.y, acc);
                    acc = fmaf(a.z, w.z, acc); acc = fmaf(a.w, w.w, acc);
                }
                for (; kk < len; ++kk) acc = fmaf(xr[kk], wl[kk], acc);
            } else {
                const float* wg = Wm + (size_t)lane * INDIM + k0;  // 8B-aligned
                int kk = 0;
                for (; kk + 4 <= len; kk += 4) {
                    float2 u0 = *(const float2*)(wg + kk);
                    float2 u1 = *(const float2*)(wg + kk + 2);
                    float4 a = *(const float4*)(xr + kk);
                    acc = fmaf(a.x, u0.x, acc); acc = fmaf(a.y, u0.y, acc);
                    acc = fmaf(a.z, u1.x, acc); acc = fmaf(a.w, u1.y, acc);
                }
                for (; kk < len; ++kk) acc = fmaf(xr[kk], wg[kk], acc);
            }
            if (g < NROWS) part[(size_t)g * (KS1 * 64) + kc * 64 + lane] = acc;
        }
    }
}

// ---- kernel 2: reduce partials + hyperbolic epilogue (hyp_bias computed inline) ----
__global__ __launch_bounds__(256) void linerB(
    const float* __restrict__ part, const float* __restrict__ pnorm,
    const float* __restrict__ bd, const float* __restrict__ bm,
    float* __restrict__ liner, float* __restrict__ xtq) {
    __shared__ float hbs[2][64];
    __shared__ float hb2s[2];
    int wave = threadIdx.x >> 6, lane = threadIdx.x & 63;
    if (wave < 2) {    // hyp_bias = proj(expmap0(bias)) for drug (wave0) / micr (wave1)
        const float* b = wave ? bm : bd;
        float v = b[lane];
        float un2 = wsum(v * v);
        float un = fmaxf(sqrtf(un2), MINN);
        float e = tanhf(un) * v / un;
        float en2 = wsum(e * e);
        float en = fmaxf(sqrtf(en2), MINN);
        float scl = (en > MAXNRM) ? (MAXNRM / en) : 1.0f;
        hbs[wave][lane] = e * scl;
        if (lane == 0) hb2s[wave] = en2 * scl * scl;
    }
    __syncthreads();

    int grow = blockIdx.x * 4 + wave;
    if (grow >= NROWS) return;
    float mx = 0.f, xn2 = 0.f;
#pragma unroll
    for (int kc = 0; kc < KS1; ++kc) mx += part[(size_t)grow * (KS1 * 64) + kc * 64 + lane];
#pragma unroll
    for (int kc = 0; kc < KS1; ++kc) xn2 += pnorm[grow * KS1 + kc];

    float mxn2 = wsum(mx * mx);
    float xn = fmaxf(sqrtf(xn2), MINN);
    float mxn = fmaxf(sqrtf(mxn2), MINN);
    float g = mxn / xn * artanh_(xn);
    float t = tanhf(g);
    float res = t * mx / mxn;              // |res| == |t|
    float rn = fabsf(t);
    if (rn > MAXNRM) { res *= MAXNRM / rn; rn = MAXNRM; }
    int mi = (grow < NDRUG) ? 0 : 1;
    float y = hbs[mi][lane];
    float y2 = hb2s[mi];
    float x2 = rn * rn;
    float xy = wsum(res * y);
    float num = (1.0f + 2.0f * xy + y2) * res + (1.0f - x2) * y;
    float den = 1.0f + 2.0f * xy + x2 * y2;
    float v = num / fmaxf(den, MINN);
    float v2 = wsum(v * v);
    float vn = fmaxf(sqrtf(v2), MINN);
    if (vn > MAXNRM) { v *= MAXNRM / vn; vn = MAXNRM; }
    float xt = artanh_(vn) / vn * v;       // logmap0
    liner[(size_t)grow * ODIM + lane] = v;
    xtq[(size_t)(grow >> 2) * QSTR + lane * 4 + (grow & 3)] = xt;  // packed for agg GEMM
}

// ---- kernel 3: split-K adj@xtan (packed xtq stream) + fused adj copy ----
__global__ __launch_bounds__(256) void gemmA_agg(
    const float* __restrict__ ADJ, const float* __restrict__ xtq,
    float* __restrict__ part, float* __restrict__ adj_out, int fuse_copy) {
    __shared__ __align__(16) float xs[8 * RSTR];
    int tid = threadIdx.x, wave = tid >> 6, lane = tid & 63;
    int row0 = blockIdx.x * 8;
    int kc = blockIdx.y;
    int k0 = kc * CH2;
    int len = min(INDIM - k0, CH2);

    {   // stage 8 rows as float2; optionally also write adj copy
        int r = tid >> 5, c0 = tid & 31;
        int gr0 = row0 + r;
        int gr = min(gr0, NROWS - 1);
        const float2* src = (const float2*)(ADJ + (size_t)gr * INDIM + k0);
        float2* dst = (float2*)&xs[r * RSTR];
        int len2 = len >> 1;
        if (fuse_copy && gr0 < NROWS) {
            float2* cp = (float2*)(adj_out + (size_t)gr0 * INDIM + k0);
            for (int c = c0; c < len2; c += 32) { float2 v = src[c]; dst[c] = v; cp[c] = v; }
        } else {
            for (int c = c0; c < len2; c += 32) dst[c] = src[c];
        }
    }
    __syncthreads();

    int r0 = 2 * wave, r1 = r0 + 1;
    int g0 = row0 + r0, g1 = g0 + 1;

    const float* xa = xs + r0 * RSTR;
    const float* xb = xs + r1 * RSTR;
    const float* wq = xtq + (size_t)(k0 >> 2) * QSTR + lane * 4;
    float acc0 = 0.f, acc1 = 0.f;
    int kk = 0;
    for (; kk + 16 <= len; kk += 16) {
        const float* wp = wq + (kk >> 2) * QSTR;
        float4 w0 = *(const float4*)(wp);
        float4 w1 = *(const float4*)(wp + QSTR);
        float4 w2 = *(const float4*)(wp + 2 * QSTR);
        float4 w3 = *(const float4*)(wp + 3 * QSTR);
        float4 a0 = *(const float4*)(xa + kk);
        float4 b0 = *(const float4*)(xb + kk);
        acc0 = fmaf(a0.x, w0.x, acc0); acc0 = fmaf(a0.y, w0.y, acc0);
        acc0 = fmaf(a0.z, w0.z, acc0); acc0 = fmaf(a0.w, w0.w, acc0);
        acc1 = fmaf(b0.x, w0.x, acc1); acc1 = fmaf(b0.y, w0.y, acc1);
        acc1 = fmaf(b0.z, w0.z, acc1); acc1 = fmaf(b0.w, w0.w, acc1);
        float4 a1 = *(const float4*)(xa + kk + 4);
        float4 b1 = *(const float4*)(xb + kk + 4);
        acc0 = fmaf(a1.x, w1.x, acc0); acc0 = fmaf(a1.y, w1.y, acc0);
        acc0 = fmaf(a1.z, w1.z, acc0); acc0 = fmaf(a1.w, w1.w, acc0);
        acc1 = fmaf(b1.x, w1.x, acc1); acc1 = fmaf(b1.y, w1.y, acc1);
        acc1 = fmaf(b1.z, w1.z, acc1); acc1 = fmaf(b1.w, w1.w, acc1);
        float4 a2 = *(const float4*)(xa + kk + 8);
        float4 b2 = *(const float4*)(xb + kk + 8);
        acc0 = fmaf(a2.x, w2.x, acc0); acc0 = fmaf(a2.y, w2.y, acc0);
        acc0 = fmaf(a2.z, w2.z, acc0); acc0 = fmaf(a2.w, w2.w, acc0);
        acc1 = fmaf(b2.x, w2.x, acc1); acc1 = fmaf(b2.y, w2.y, acc1);
        acc1 = fmaf(b2.z, w2.z, acc1); acc1 = fmaf(b2.w, w2.w, acc1);
        float4 a3 = *(const float4*)(xa + kk + 12);
        float4 b3 = *(const float4*)(xb + kk + 12);
        acc0 = fmaf(a3.x, w3.x, acc0); acc0 = fmaf(a3.y, w3.y, acc0);
        acc0 = fmaf(a3.z, w3.z, acc0); acc0 = fmaf(a3.w, w3.w, acc0);
        acc1 = fmaf(b3.x, w3.x, acc1); acc1 = fmaf(b3.y, w3.y, acc1);
        acc1 = fmaf(b3.z, w3.z, acc1); acc1 = fmaf(b3.w, w3.w, acc1);
    }
    for (; kk + 4 <= len; kk += 4) {
        float4 w = *(const float4*)(wq + (kk >> 2) * QSTR);
        float4 a = *(const float4*)(xa + kk);
        float4 b = *(const float4*)(xb + kk);
        acc0 = fmaf(a.x, w.x, acc0); acc0 = fmaf(a.y, w.y, acc0);
        acc0 = fmaf(a.z, w.z, acc0); acc0 = fmaf(a.w, w.w, acc0);
        acc1 = fmaf(b.x, w.x, acc1); acc1 = fmaf(b.y, w.y, acc1);
        acc1 = fmaf(b.z, w.z, acc1); acc1 = fmaf(b.w, w.w, acc1);
    }
    for (; kk < len; ++kk) {
        float w = wq[(kk >> 2) * QSTR + (kk & 3)];
        acc0 = fmaf(xa[kk], w, acc0);
        acc1 = fmaf(xb[kk], w, acc1);
    }
    if (g0 < NROWS) part[(size_t)g0 * (KS2 * 64) + kc * 64 + lane] = acc0;
    if (g1 < NROWS) part[(size_t)g1 * (KS2 * 64) + kc * 64 + lane] = acc1;
}

// ---- kernel 4: reduce partials + expmap0/proj + gated HypAct -> h ----
__global__ __launch_bounds__(256) void aggB(
    const float* __restrict__ part, const float* __restrict__ liner,
    const float* __restrict__ WN /*[128][64]*/, const float* __restrict__ biasnode,
    float* __restrict__ out_h) {
    __shared__ float zl[4][128];
    int wave = threadIdx.x >> 6, lane = threadIdx.x & 63;
    int grow = blockIdx.x * 4 + wave;
    if (grow >= NROWS) return;
    float s = 0.f;
#pragma unroll
    for (int kc = 0; kc < KS2; ++kc) s += part[(size_t)grow * (KS2 * 64) + kc * 64 + lane];
    float sn2 = wsum(s * s);
    float sn = fmaxf(sqrtf(sn2), MINN);
    float th = tanhf(sn);
    float agg = th * s / sn;               // expmap0; |agg| == th
    if (th > MAXNRM) agg *= MAXNRM / th;
    float lin = liner[(size_t)grow * ODIM + lane];
    zl[wave][lane] = agg;
    zl[wave][64 + lane] = lin;             // same-wave LDS RAW, no barrier needed
    float d = biasnode[grow];
    const float* w = WN + lane;
#pragma unroll 8
    for (int f = 0; f < 128; ++f) d = fmaf(zl[wave][f], w[f * 64], d);
    d = fmaxf(d, 0.0f);
    out_h[(size_t)grow * ODIM + lane] = d * agg + (1.0f - d) * lin;
}

// ---- fallback: copy adj into second tuple output ----
__global__ void copy_adj(const float4* __restrict__ src, float4* __restrict__ dst, int n4) {
    for (int i = blockIdx.x * blockDim.x + threadIdx.x; i < n4; i += gridDim.x * blockDim.x)
        dst[i] = src[i];
}

extern "C" void kernel_launch(void* const* d_in, const int* in_sizes, int n_in,
                              void* d_out, int out_size, void* d_ws, size_t ws_size,
                              hipStream_t stream) {
    const float* x   = (const float*)d_in[0];
    const float* adj = (const float*)d_in[1];
    const float* Wd  = (const float*)d_in[2];
    const float* Wm  = (const float*)d_in[3];
    const float* bd  = (const float*)d_in[4];
    const float* bm  = (const float*)d_in[5];
    const float* wn  = (const float*)d_in[6];
    const float* bn  = (const float*)d_in[7];
    float* out = (float*)d_out;
    float* ws  = (float*)d_ws;

    const int WELEMS = ODIM * INDIM;          // 98944
    const int QELEMS = NQ * QSTR;             // 99072
    float* liner = ws;                        // 98944
    float* xtq   = liner + WELEMS;            // 99072 (packed)
    float* pnorm = xtq + QELEMS;              // 1546*16 = 24736
    float* ws_end = pnorm + 24736;
    size_t used = (size_t)(ws_end - ws);
    size_t part_off = (used + 63) & ~(size_t)63;
    const size_t PARTN = (size_t)NROWS * KS1 * 64;    // 1583104 (covers KS2 too)
    size_t need = (part_off + PARTN) * sizeof(float);
    int fast = (ws_size >= need);
    float* part = fast ? (ws + part_off) : (out + WELEMS);   // adjout region holds it

    dim3 g1(NRG, KS1);
    gemm_liner<<<g1, 256, 0, stream>>>(x, Wd, Wm, part, pnorm);
    linerB<<<387, 256, 0, stream>>>(part, pnorm, bd, bm, liner, xtq);
    dim3 g2(NRG, KS2);
    gemmA_agg<<<g2, 256, 0, stream>>>(adj, xtq, part, out + WELEMS, fast);
    aggB<<<387, 256, 0, stream>>>(part, liner, wn, bn, out);

    if (!fast) {
        int n4 = (NROWS * NROWS) / 4;
        copy_adj<<<(n4 + 255) / 256, 256, 0, stream>>>((const float4*)adj,
                                                       (float4*)(out + WELEMS), n4);
    }
}

// Round 11
// 46.156 us; speedup vs baseline: 1.2902x; 1.2902x over previous
//
#include <hip/hip_runtime.h>
#include <math.h>

#define NROWS 1546
#define INDIM 1546
#define ODIM  64
#define NDRUG 1373
#define MINN  1e-15f
#define MAXNRM 0.996f   // (1 - 4e-3)/sqrt(c), c=1

#define KS   8          // K-splits (blocks in y)
#define CH   200        // 4-aligned K-chunk; last chunk = 1546-7*200 = 146
#define RSTR 200        // LDS row stride in floats (800B per row, 16B-aligned)
#define NRG  194        // row-groups of 8
#define QSTR 256        // packed quad stride: idx = (k>>2)*QSTR + col*4 + (k&3)
#define NQ   387        // ceil(1546/4)

__device__ __forceinline__ float artanh_(float x) {
    x = fminf(fmaxf(x, -1.0f + 1e-7f), 1.0f - 1e-7f);
    return 0.5f * (log1pf(x) - log1pf(-x));
}

__device__ __forceinline__ float wsum(float v) {
#pragma unroll
    for (int off = 32; off > 0; off >>= 1) v += __shfl_xor(v, off, 64);
    return v;
}

// ---- kernel 1: W[64][1546] -> packed Wq (both), bias prep (last block) ----
__global__ void prep_kernel(const float* __restrict__ Wd, const float* __restrict__ Wm,
                            float* __restrict__ WqD, float* __restrict__ WqM,
                            const float* __restrict__ bd, const float* __restrict__ bm,
                            float* __restrict__ hbD, float* __restrict__ hbM,
                            float* __restrict__ hb2) {
    if (blockIdx.x == gridDim.x - 1) {
        int tid = threadIdx.x;
        if (tid < 128) {
            int wave = tid >> 6, lane = tid & 63;
            const float* b = wave ? bm : bd;
            float v = b[lane];
            float un2 = wsum(v * v);
            float un = fmaxf(sqrtf(un2), MINN);
            float e = tanhf(un) * v / un;
            float en2 = wsum(e * e);
            float en = fmaxf(sqrtf(en2), MINN);
            float scl = (en > MAXNRM) ? (MAXNRM / en) : 1.0f;
            e *= scl;
            float* hb = wave ? hbM : hbD;
            hb[lane] = e;
            if (lane == 0) hb2[wave] = en2 * scl * scl;
        }
        return;
    }
    int nblk = gridDim.x - 1;
    int total = ODIM * INDIM;
    for (int i = blockIdx.x * blockDim.x + threadIdx.x; i < total; i += nblk * blockDim.x) {
        int o = i / INDIM;
        int k = i - o * INDIM;
        int qi = (k >> 2) * QSTR + o * 4 + (k & 3);
        WqD[qi] = Wd[i];
        WqM[qi] = Wm[i];
    }
}

// ---- kernel 2: split-K x@W^T; waves K-split the shared Wq stream, LDS reduce ----
__global__ __launch_bounds__(256) void gemmA_liner(
    const float* __restrict__ X, const float* __restrict__ WqD, const float* __restrict__ WqM,
    float* __restrict__ part, float* __restrict__ pnorm) {
    __shared__ __align__(16) float xs[8 * RSTR];
    __shared__ float red[4][8][64];
    int tid = threadIdx.x, wave = tid >> 6, lane = tid & 63;
    int row0 = blockIdx.x * 8;
    int kc = blockIdx.y;
    int k0 = kc * CH;               // multiple of 4
    int len = min(INDIM - k0, CH);  // 200 or 146 (even)

    {   // stage 8 rows x len as float2 (32 threads per row) + fused partial norms
        int r = tid >> 5, c0 = tid & 31;
        int gr = min(row0 + r, NROWS - 1);
        const float2* src = (const float2*)(X + (size_t)gr * INDIM + k0);
        float2* dst = (float2*)&xs[r * RSTR];
        int len2 = len >> 1;
        float ss = 0.f;
        for (int c = c0; c < len2; c += 32) {
            float2 v = src[c];
            dst[c] = v;
            ss = fmaf(v.x, v.x, fmaf(v.y, v.y, ss));
        }
#pragma unroll
        for (int off = 16; off > 0; off >>= 1) ss += __shfl_xor(ss, off, 64);
        if (c0 == 0 && row0 + r < NROWS) pnorm[(row0 + r) * KS + kc] = ss;
    }
    __syncthreads();

    float acc[8];
#pragma unroll
    for (int r = 0; r < 8; ++r) acc[r] = 0.f;

    int nq = len >> 2;                       // 50 or 36
    int qoff = (k0 >> 2) * QSTR + lane * 4;
    bool uni = (row0 + 7 < NDRUG) || (row0 >= NDRUG);
    if (uni) {
        const float* wq = ((row0 < NDRUG) ? WqD : WqM) + qoff;
        for (int q = wave; q < nq; q += 4) { // each wave owns a strided quad subset
            float4 w = *(const float4*)(wq + q * QSTR);
#pragma unroll
            for (int r = 0; r < 8; ++r) {    // x reads: wave-uniform LDS broadcast
                float4 a = *(const float4*)(xs + r * RSTR + 4 * q);
                acc[r] = fmaf(a.x, w.x, acc[r]); acc[r] = fmaf(a.y, w.y, acc[r]);
                acc[r] = fmaf(a.z, w.z, acc[r]); acc[r] = fmaf(a.w, w.w, acc[r]);
            }
        }
    } else {
        // single boundary row-group (rows straddle 1373): load both, select per row
        const float* wqd = WqD + qoff;
        const float* wqm = WqM + qoff;
        for (int q = wave; q < nq; q += 4) {
            float4 wd = *(const float4*)(wqd + q * QSTR);
            float4 wm = *(const float4*)(wqm + q * QSTR);
#pragma unroll
            for (int r = 0; r < 8; ++r) {
                bool dd = (row0 + r) < NDRUG;
                float4 w;
                w.x = dd ? wd.x : wm.x; w.y = dd ? wd.y : wm.y;
                w.z = dd ? wd.z : wm.z; w.w = dd ? wd.w : wm.w;
                float4 a = *(const float4*)(xs + r * RSTR + 4 * q);
                acc[r] = fmaf(a.x, w.x, acc[r]); acc[r] = fmaf(a.y, w.y, acc[r]);
                acc[r] = fmaf(a.z, w.z, acc[r]); acc[r] = fmaf(a.w, w.w, acc[r]);
            }
        }
    }
    if (wave == 0) {                         // scalar K tail (len=146: k=144,145)
        const float* wqd = WqD + qoff;
        const float* wqm = WqM + qoff;
        for (int k = nq << 2; k < len; ++k) {
            float wdv = wqd[(k >> 2) * QSTR + (k & 3)];
            float wmv = wqm[(k >> 2) * QSTR + (k & 3)];
#pragma unroll
            for (int r = 0; r < 8; ++r) {
                float w = (row0 + r < NDRUG) ? wdv : wmv;
                acc[r] = fmaf(xs[r * RSTR + k], w, acc[r]);
            }
        }
    }

#pragma unroll
    for (int r = 0; r < 8; ++r) red[wave][r][lane] = acc[r];
    __syncthreads();
#pragma unroll
    for (int j = 0; j < 2; ++j) {            // cross-wave reduce: 2-way bank alias = free
        int r = 2 * wave + j;
        int g = row0 + r;
        if (g < NROWS) {
            float s = red[0][r][lane] + red[1][r][lane] + red[2][r][lane] + red[3][r][lane];
            part[(size_t)g * (KS * 64) + kc * 64 + lane] = s;
        }
    }
}

// ---- kernel 3: reduce partials + hyperbolic epilogue -> liner (plain), xtq (packed) ----
__global__ __launch_bounds__(512) void linerB(
    const float* __restrict__ part, const float* __restrict__ pnorm,
    const float* __restrict__ hbD, const float* __restrict__ hbM, const float* __restrict__ hb2v,
    float* __restrict__ liner, float* __restrict__ xtq) {
    int wave = threadIdx.x >> 6, lane = threadIdx.x & 63;
    int grow = blockIdx.x * 8 + wave;
    if (grow >= NROWS) return;
    float mx = 0.f, xn2 = 0.f;
#pragma unroll
    for (int kc = 0; kc < KS; ++kc) mx += part[(size_t)grow * (KS * 64) + kc * 64 + lane];
#pragma unroll
    for (int kc = 0; kc < KS; ++kc) xn2 += pnorm[grow * KS + kc];

    float mxn2 = wsum(mx * mx);
    float xn = fmaxf(sqrtf(xn2), MINN);
    float mxn = fmaxf(sqrtf(mxn2), MINN);
    float g = mxn / xn * artanh_(xn);
    float t = tanhf(g);
    float res = t * mx / mxn;              // |res| == |t|
    float rn = fabsf(t);
    if (rn > MAXNRM) { res *= MAXNRM / rn; rn = MAXNRM; }
    const float* hb = (grow < NDRUG) ? hbD : hbM;
    float y = hb[lane];
    float y2 = hb2v[(grow < NDRUG) ? 0 : 1];
    float x2 = rn * rn;
    float xy = wsum(res * y);
    float num = (1.0f + 2.0f * xy + y2) * res + (1.0f - x2) * y;
    float den = 1.0f + 2.0f * xy + x2 * y2;
    float v = num / fmaxf(den, MINN);
    float v2 = wsum(v * v);
    float vn = fmaxf(sqrtf(v2), MINN);
    if (vn > MAXNRM) { v *= MAXNRM / vn; vn = MAXNRM; }
    float xt = artanh_(vn) / vn * v;       // logmap0
    liner[(size_t)grow * ODIM + lane] = v;
    xtq[(size_t)(grow >> 2) * QSTR + lane * 4 + (grow & 3)] = xt;  // packed for agg GEMM
}

// ---- kernel 4: split-K adj@xtan; waves K-split shared xtq stream, fused adj copy ----
__global__ __launch_bounds__(256) void gemmA_agg(
    const float* __restrict__ ADJ, const float* __restrict__ xtq,
    float* __restrict__ part, float* __restrict__ adj_out, int fuse_copy) {
    __shared__ __align__(16) float xs[8 * RSTR];
    __shared__ float red[4][8][64];
    int tid = threadIdx.x, wave = tid >> 6, lane = tid & 63;
    int row0 = blockIdx.x * 8;
    int kc = blockIdx.y;
    int k0 = kc * CH;
    int len = min(INDIM - k0, CH);

    {   // stage 8 rows as float2; optionally also write adj copy
        int r = tid >> 5, c0 = tid & 31;
        int gr0 = row0 + r;
        int gr = min(gr0, NROWS - 1);
        const float2* src = (const float2*)(ADJ + (size_t)gr * INDIM + k0);
        float2* dst = (float2*)&xs[r * RSTR];
        int len2 = len >> 1;
        if (fuse_copy && gr0 < NROWS) {
            float2* cp = (float2*)(adj_out + (size_t)gr0 * INDIM + k0);
            for (int c = c0; c < len2; c += 32) { float2 v = src[c]; dst[c] = v; cp[c] = v; }
        } else {
            for (int c = c0; c < len2; c += 32) dst[c] = src[c];
        }
    }
    __syncthreads();

    float acc[8];
#pragma unroll
    for (int r = 0; r < 8; ++r) acc[r] = 0.f;

    int nq = len >> 2;
    const float* wq = xtq + (size_t)(k0 >> 2) * QSTR + lane * 4;
    for (int q = wave; q < nq; q += 4) {
        float4 w = *(const float4*)(wq + q * QSTR);
#pragma unroll
        for (int r = 0; r < 8; ++r) {
            float4 a = *(const float4*)(xs + r * RSTR + 4 * q);
            acc[r] = fmaf(a.x, w.x, acc[r]); acc[r] = fmaf(a.y, w.y, acc[r]);
            acc[r] = fmaf(a.z, w.z, acc[r]); acc[r] = fmaf(a.w, w.w, acc[r]);
        }
    }
    if (wave == 0) {
        for (int k = nq << 2; k < len; ++k) {
            float w = wq[(k >> 2) * QSTR + (k & 3)];
#pragma unroll
            for (int r = 0; r < 8; ++r) acc[r] = fmaf(xs[r * RSTR + k], w, acc[r]);
        }
    }

#pragma unroll
    for (int r = 0; r < 8; ++r) red[wave][r][lane] = acc[r];
    __syncthreads();
#pragma unroll
    for (int j = 0; j < 2; ++j) {
        int r = 2 * wave + j;
        int g = row0 + r;
        if (g < NROWS) {
            float s = red[0][r][lane] + red[1][r][lane] + red[2][r][lane] + red[3][r][lane];
            part[(size_t)g * (KS * 64) + kc * 64 + lane] = s;
        }
    }
}

// ---- kernel 5: reduce partials + expmap0/proj + gated HypAct -> h ----
__global__ __launch_bounds__(512) void aggB(
    const float* __restrict__ part, const float* __restrict__ liner,
    const float* __restrict__ WN /*[128][64]*/, const float* __restrict__ biasnode,
    float* __restrict__ out_h) {
    __shared__ float zl[8][128];
    int wave = threadIdx.x >> 6, lane = threadIdx.x & 63;
    int grow = blockIdx.x * 8 + wave;
    if (grow >= NROWS) return;
    float s = 0.f;
#pragma unroll
    for (int kc = 0; kc < KS; ++kc) s += part[(size_t)grow * (KS * 64) + kc * 64 + lane];
    float sn2 = wsum(s * s);
    float sn = fmaxf(sqrtf(sn2), MINN);
    float th = tanhf(sn);
    float agg = th * s / sn;               // expmap0; |agg| == th
    if (th > MAXNRM) agg *= MAXNRM / th;
    float lin = liner[(size_t)grow * ODIM + lane];
    zl[wave][lane] = agg;
    zl[wave][64 + lane] = lin;             // same-wave LDS RAW, no barrier needed
    float d = biasnode[grow];
    const float* w = WN + lane;
#pragma unroll 8
    for (int f = 0; f < 128; ++f) d = fmaf(zl[wave][f], w[f * 64], d);
    d = fmaxf(d, 0.0f);
    out_h[(size_t)grow * ODIM + lane] = d * agg + (1.0f - d) * lin;
}

// ---- fallback: copy adj into second tuple output ----
__global__ void copy_adj(const float4* __restrict__ src, float4* __restrict__ dst, int n4) {
    for (int i = blockIdx.x * blockDim.x + threadIdx.x; i < n4; i += gridDim.x * blockDim.x)
        dst[i] = src[i];
}

extern "C" void kernel_launch(void* const* d_in, const int* in_sizes, int n_in,
                              void* d_out, int out_size, void* d_ws, size_t ws_size,
                              hipStream_t stream) {
    const float* x   = (const float*)d_in[0];
    const float* adj = (const float*)d_in[1];
    const float* Wd  = (const float*)d_in[2];
    const float* Wm  = (const float*)d_in[3];
    const float* bd  = (const float*)d_in[4];
    const float* bm  = (const float*)d_in[5];
    const float* wn  = (const float*)d_in[6];
    const float* bn  = (const float*)d_in[7];
    float* out = (float*)d_out;
    float* ws  = (float*)d_ws;

    const int WELEMS = ODIM * INDIM;          // 98944
    const int QELEMS = NQ * QSTR;             // 99072
    float* WqD   = ws;                        // 99072
    float* WqM   = WqD + QELEMS;              // 99072
    float* hbD   = WqM + QELEMS;              // 64
    float* hbM   = hbD + 64;                  // 64
    float* hb2   = hbM + 64;                  // 2 (+pad)
    float* liner = hbD + 192;                 // 98944
    float* xtq   = liner + WELEMS;            // 99072 (packed)
    float* pnorm = xtq + QELEMS;              // 1546*8 = 12368
    float* ws_end = pnorm + 12368;
    size_t used = (size_t)(ws_end - ws);
    size_t part_off = (used + 63) & ~(size_t)63;
    size_t need = (part_off + (size_t)NROWS * KS * 64) * sizeof(float);
    int fast = (ws_size >= need);
    float* part = fast ? (ws + part_off) : (out + WELEMS);

    prep_kernel<<<388, 256, 0, stream>>>(Wd, Wm, WqD, WqM, bd, bm, hbD, hbM, hb2);

    dim3 gA(NRG, KS);
    gemmA_liner<<<gA, 256, 0, stream>>>(x, WqD, WqM, part, pnorm);
    linerB<<<NRG, 512, 0, stream>>>(part, pnorm, hbD, hbM, hb2, liner, xtq);
    gemmA_agg<<<gA, 256, 0, stream>>>(adj, xtq, part, out + WELEMS, fast);
    aggB<<<NRG, 512, 0, stream>>>(part, liner, wn, bn, out);

    if (!fast) {
        int n4 = (NROWS * NROWS) / 4;
        copy_adj<<<(n4 + 255) / 256, 256, 0, stream>>>((const float4*)adj,
                                                       (float4*)(out + WELEMS), n4);
    }
}